// Round 11
// baseline (165.955 us; speedup 1.0000x reference)
//
#include <hip/hip_runtime.h>
#include <stdint.h>

#define S_LEN 2048
#define BATCH 2
#define DMODEL 1024
#define NHEAD 16
#define DK 64
#define MROWS (BATCH * S_LEN) /* 4096 */

typedef __attribute__((ext_vector_type(8))) short bf16x8;
typedef __attribute__((ext_vector_type(4))) float f32x4;
typedef __attribute__((ext_vector_type(4))) short short4v;
typedef __attribute__((ext_vector_type(2))) uint32_t u32x2;

__device__ __forceinline__ short f2b(float f) {
    union { float f; uint32_t u; } c; c.f = f;
    uint32_t u = c.u;
    return (short)((u + 0x7fffu + ((u >> 16) & 1u)) >> 16);
}

__device__ __forceinline__ void gload16(const void* g, void* l) {
    __builtin_amdgcn_global_load_lds(
        (const __attribute__((address_space(1))) void*)g,
        (__attribute__((address_space(3))) void*)l, 16, 0, 0);
}

// ---------------------------------------------------------------- fp32 -> bf16
__global__ void cvt_kernel(const float* __restrict__ X, const float* __restrict__ Wq,
                           const float* __restrict__ Wk, const float* __restrict__ Wv,
                           const float* __restrict__ Wo,
                           short* __restrict__ Xb, short* __restrict__ Wqb,
                           short* __restrict__ Wkb, short* __restrict__ Wvb,
                           short* __restrict__ Wob) {
    const float* src; short* dst; int n4;
    switch (blockIdx.y) {
        case 0:  src = X;  dst = Xb;  n4 = MROWS * DMODEL / 4;  break;
        case 1:  src = Wq; dst = Wqb; n4 = DMODEL * DMODEL / 4; break;
        case 2:  src = Wk; dst = Wkb; n4 = DMODEL * DMODEL / 4; break;
        case 3:  src = Wv; dst = Wvb; n4 = DMODEL * DMODEL / 4; break;
        default: src = Wo; dst = Wob; n4 = DMODEL * DMODEL / 4; break;
    }
    for (int i = blockIdx.x * blockDim.x + threadIdx.x; i < n4;
         i += gridDim.x * blockDim.x) {
        float4 v = ((const float4*)src)[i];
        short4v o;
        o[0] = f2b(v.x); o[1] = f2b(v.y); o[2] = f2b(v.z); o[3] = f2b(v.w);
        ((short4v*)dst)[i] = o;
    }
}

// ------------------------------------------------- C = A * Bt^T  (bf16 MFMA)
// Double-buffered LDS, ONE barrier per K-step; XOR-swizzled tiles (conflicts=0).
// z==2 (V) writes TRANSPOSED per-head: Vt[b][h][d][key], packed 4xbf16 stores.
template <int OUT_F32>
__global__ __launch_bounds__(256) void gemm_bt(
    const short* __restrict__ A,
    const short* __restrict__ Bt0, const short* __restrict__ Bt1,
    const short* __restrict__ Bt2,
    short* __restrict__ Cb0, short* __restrict__ Cb1, short* __restrict__ Cb2,
    float* __restrict__ Cf, int M, int N, int K) {
    __shared__ short sA[2][128 * 32];
    __shared__ short sB[2][128 * 32];

    const short* Bt = Bt0;
    short* Cb = Cb0;
    if (blockIdx.z == 1) { Bt = Bt1; Cb = Cb1; }
    else if (blockIdx.z == 2) { Bt = Bt2; Cb = Cb2; }

    const int tid = threadIdx.x;
    const int lane = tid & 63;
    const int wid = tid >> 6;
    const int wr = wid >> 1, wc = wid & 1;
    const int brow = blockIdx.y * 128;
    const int bcol = blockIdx.x * 128;
    const int lr = lane & 15;
    const int kh = (lane >> 4) << 3;
    const int swg = ((lr >> 1) & 3) << 3;   // read-side swizzle (lane-invariant)
    const int khs = kh ^ swg;

    f32x4 acc[4][4] = {};

    const int idx0 = tid, idx1 = tid + 256;
    const int ar0 = idx0 >> 2, ak0 = ((idx0 & 3) << 3) ^ (((ar0 >> 1) & 3) << 3);
    const int ar1 = idx1 >> 2, ak1 = ((idx1 & 3) << 3) ^ (((ar1 >> 1) & 3) << 3);

    const short* gA0 = A + (size_t)(brow + ar0) * K + ak0;
    const short* gA1 = A + (size_t)(brow + ar1) * K + ak1;
    const short* gB0 = Bt + (size_t)(bcol + ar0) * K + ak0;
    const short* gB1 = Bt + (size_t)(bcol + ar1) * K + ak1;

    const int nk = K >> 5;
    // prologue: stage K-tile 0 into buffer 0
    gload16(gA0, &sA[0][idx0 * 8]);
    gload16(gA1, &sA[0][idx1 * 8]);
    gload16(gB0, &sB[0][idx0 * 8]);
    gload16(gB1, &sB[0][idx1 * 8]);
    __syncthreads();

    int cur = 0;
    for (int kt = 0; kt < nk; ++kt) {
        if (kt + 1 < nk) {
            const int k0 = (kt + 1) << 5;
            gload16(gA0 + k0, &sA[cur ^ 1][idx0 * 8]);
            gload16(gA1 + k0, &sA[cur ^ 1][idx1 * 8]);
            gload16(gB0 + k0, &sB[cur ^ 1][idx0 * 8]);
            gload16(gB1 + k0, &sB[cur ^ 1][idx1 * 8]);
        }

        bf16x8 a[4], b[4];
#pragma unroll
        for (int mt = 0; mt < 4; ++mt)
            a[mt] = *(const bf16x8*)&sA[cur][(wr * 64 + mt * 16 + lr) * 32 + khs];
#pragma unroll
        for (int nt = 0; nt < 4; ++nt)
            b[nt] = *(const bf16x8*)&sB[cur][(wc * 64 + nt * 16 + lr) * 32 + khs];
        __builtin_amdgcn_s_setprio(1);
#pragma unroll
        for (int mt = 0; mt < 4; ++mt)
#pragma unroll
            for (int nt = 0; nt < 4; ++nt)
                acc[mt][nt] = __builtin_amdgcn_mfma_f32_16x16x32_bf16(
                    a[mt], b[nt], acc[mt][nt], 0, 0, 0);
        __builtin_amdgcn_s_setprio(0);

        __syncthreads();
        cur ^= 1;
    }

    const int rbase = (lane >> 4) << 2;
    const bool vtrans = (!OUT_F32) && (blockIdx.z == 2);
#pragma unroll
    for (int mt = 0; mt < 4; ++mt) {
#pragma unroll
        for (int nt = 0; nt < 4; ++nt) {
            if (vtrans) {
                int row0 = brow + wr * 64 + mt * 16 + rbase;  // key (4 consecutive)
                int col = bcol + wc * 64 + nt * 16 + lr;
                int bb = row0 >> 11, key = row0 & 2047;
                int hh = col >> 6, d = col & 63;
                short4v pk;
#pragma unroll
                for (int j = 0; j < 4; ++j) pk[j] = f2b(acc[mt][nt][j]);
                *(short4v*)&Cb[((size_t)((bb * 16 + hh) * 64 + d)) * S_LEN + key] = pk;
            } else {
#pragma unroll
                for (int j = 0; j < 4; ++j) {
                    int row = brow + wr * 64 + mt * 16 + rbase + j;
                    int col = bcol + wc * 64 + nt * 16 + lr;
                    if (OUT_F32)
                        Cf[(size_t)row * N + col] = acc[mt][nt][j];
                    else
                        Cb[(size_t)row * N + col] = f2b(acc[mt][nt][j]);
                }
            }
        }
    }
}

// ------------------------------------------------------------- flash attention
// ZERO-barrier version: K and Vt fragments are read DIRECTLY from global
// (L2-resident: 512KB per (b,h), 4 (b,h) pinned per XCD via id%8 mapping).
// 2048 blocks x 1 wave; wave owns 32 q-rows as two 16-row fragments sharing
// every K/V load. Only LDS use: per-wave 2x2KB P buffer (ds ops wave-ordered,
// no sync needed). Swapped QK^T / swapped PV, lane-local softmax, defer-max.
__global__ __launch_bounds__(64, 4) void attn_kernel(
    const short* __restrict__ Q, const short* __restrict__ K,
    const short* __restrict__ Vt, short* __restrict__ O,
    const int* __restrict__ vlens) {
    __shared__ short sP[2][16 * 64];

    const int lane = threadIdx.x;
    // XCD pinning: blocks of one (b,h) all have id%8 == bhx%8.
    const int id = blockIdx.x;
    const int xcd = id & 7;
    const int k_ = id >> 3;
    const int qb = k_ & 63;               // 64 q-tiles of 32 rows
    const int g = k_ >> 6;                // 0..3
    const int bhx = xcd + 8 * g;
    const int b = bhx & 1, h = bhx >> 1;
    const int lr = lane & 15;
    const int kh = (lane >> 4) << 3;
    const int rbase = (lane >> 4) << 2;
    const int swq = (lr & 7) << 3;

    int vl = vlens[b];
    if (vl < 0) vl = 0;
    if (vl > S_LEN) vl = S_LEN;
    const bool allm = (vl == 0);
    if (allm) vl = S_LEN;  // qf=0 -> scores 0 -> uniform softmax == reference
    const int nT = (vl + 63) >> 6;
    const int nFull = ((vl & 63) == 0) ? nT : nT - 1;

    const size_t rowbase = (size_t)(b * S_LEN) * DMODEL + h * DK;
    const short* vt = Vt + ((size_t)((b * 16 + h) * 64)) * S_LEN;

    const short* qrowA = Q + rowbase + (size_t)(qb * 32 + lr) * DMODEL;
    const short* qrowB = qrowA + 16 * DMODEL;
    bf16x8 qf0a = *(const bf16x8*)(qrowA + kh);
    bf16x8 qf1a = *(const bf16x8*)(qrowA + 32 + kh);
    bf16x8 qf0b = *(const bf16x8*)(qrowB + kh);
    bf16x8 qf1b = *(const bf16x8*)(qrowB + 32 + kh);
    if (allm) {
#pragma unroll
        for (int i = 0; i < 8; ++i) { qf0a[i] = 0; qf1a[i] = 0; qf0b[i] = 0; qf1b[i] = 0; }
    }

    f32x4 oacA[4] = {}, oacB[4] = {};
    float mA = -1e30f, mcA = -1e30f, lA = 0.f;
    float mB = -1e30f, mcB = -1e30f, lB = 0.f;
    const float CEXP = 0.18033688011112042f;   // 0.125 * log2(e)
    const float THRADD = 44.361419556f;        // 8 / CEXP

    // per-lane running global pointers (advance 64 keys per tile)
    const short* kRun = K + rowbase + (size_t)lr * DMODEL + kh;   // row=key frag
    const short* vRun = vt + (size_t)lr * S_LEN + kh;             // row=d frag

    // P LDS geometry
    const int lofs0 = lr * 64 + (kh ^ swq);
    const int lofs1 = lr * 64 + ((32 + kh) ^ swq);

#define SOFTMAX_FRAG(SACC, MRUN, MC, LRUN, OAC, SPW)                            \
    do {                                                                        \
        float t0 = fmaxf(fmaxf(SACC[0][0], SACC[0][1]), SACC[0][2]);            \
        float t1 = fmaxf(fmaxf(SACC[0][3], SACC[1][0]), SACC[1][1]);            \
        float t2 = fmaxf(fmaxf(SACC[1][2], SACC[1][3]), SACC[2][0]);            \
        float t3 = fmaxf(fmaxf(SACC[2][1], SACC[2][2]), SACC[2][3]);            \
        float t4 = fmaxf(fmaxf(SACC[3][0], SACC[3][1]), SACC[3][2]);            \
        float pmax = fmaxf(fmaxf(fmaxf(t0, t1), t2),                            \
                           fmaxf(fmaxf(t3, t4), SACC[3][3]));                   \
        if (__any(pmax > MRUN + THRADD)) {                                      \
            float mx = pmax;                                                    \
            mx = fmaxf(mx, __shfl_xor(mx, 16));                                 \
            mx = fmaxf(mx, __shfl_xor(mx, 32));                                 \
            float scl = __builtin_exp2f((MRUN - mx) * CEXP);                    \
            MRUN = mx;                                                          \
            MC = mx * CEXP;                                                     \
            LRUN *= scl;                                                        \
            _Pragma("unroll")                                                   \
            for (int dt = 0; dt < 4; ++dt)                                      \
                _Pragma("unroll")                                               \
                for (int j = 0; j < 4; ++j) OAC[dt][j] *= scl;                  \
        }                                                                       \
        float p[16];                                                            \
        _Pragma("unroll")                                                       \
        for (int nt = 0; nt < 4; ++nt)                                          \
            _Pragma("unroll")                                                   \
            for (int j = 0; j < 4; ++j)                                         \
                p[nt * 4 + j] = __builtin_exp2f(                                \
                    __builtin_fmaf(SACC[nt][j], CEXP, -MC));                    \
        float ls = ((p[0] + p[1]) + (p[2] + p[3])) +                            \
                   ((p[4] + p[5]) + (p[6] + p[7]));                             \
        ls += ((p[8] + p[9]) + (p[10] + p[11])) +                               \
              ((p[12] + p[13]) + (p[14] + p[15]));                              \
        LRUN += ls;                                                             \
        _Pragma("unroll")                                                       \
        for (int nt = 0; nt < 4; ++nt) {                                        \
            u32x2 r;                                                            \
            asm("v_cvt_pk_bf16_f32 %0, %1, %2"                                  \
                : "=v"(r[0]) : "v"(p[nt * 4 + 0]), "v"(p[nt * 4 + 1]));         \
            asm("v_cvt_pk_bf16_f32 %0, %1, %2"                                  \
                : "=v"(r[1]) : "v"(p[nt * 4 + 2]), "v"(p[nt * 4 + 3]));         \
            *(u32x2*)&SPW[lr * 64 + ((nt * 16 + rbase) ^ swq)] = r;             \
        }                                                                       \
    } while (0)

#define TILE_BODY(MASKED_C)                                                     \
    do {                                                                        \
        constexpr bool MASKED = MASKED_C;                                       \
        f32x4 saccA[4] = {}, saccB[4] = {};                                     \
        __builtin_amdgcn_s_setprio(1);                                          \
        _Pragma("unroll")                                                       \
        for (int nt = 0; nt < 4; ++nt) {                                        \
            bf16x8 kb0 = *(const bf16x8*)(kRun + (size_t)(nt * 16) * DMODEL);   \
            bf16x8 kb1 = *(const bf16x8*)(kRun + (size_t)(nt * 16) * DMODEL + 32); \
            saccA[nt] = __builtin_amdgcn_mfma_f32_16x16x32_bf16(                \
                kb0, qf0a, saccA[nt], 0, 0, 0);                                 \
            saccB[nt] = __builtin_amdgcn_mfma_f32_16x16x32_bf16(                \
                kb0, qf0b, saccB[nt], 0, 0, 0);                                 \
            saccA[nt] = __builtin_amdgcn_mfma_f32_16x16x32_bf16(                \
                kb1, qf1a, saccA[nt], 0, 0, 0);                                 \
            saccB[nt] = __builtin_amdgcn_mfma_f32_16x16x32_bf16(                \
                kb1, qf1b, saccB[nt], 0, 0, 0);                                 \
        }                                                                       \
        __builtin_amdgcn_s_setprio(0);                                          \
        if (MASKED) {                                                           \
            _Pragma("unroll")                                                   \
            for (int nt = 0; nt < 4; ++nt)                                      \
                _Pragma("unroll")                                               \
                for (int j = 0; j < 4; ++j) {                                   \
                    int keyi = t * 64 + nt * 16 + rbase + j;                    \
                    if (keyi >= vl) { saccA[nt][j] = -3.0e38f;                  \
                                      saccB[nt][j] = -3.0e38f; }                \
                }                                                               \
        }                                                                       \
        SOFTMAX_FRAG(saccA, mA, mcA, lA, oacA, (&sP[0][0]));                    \
        SOFTMAX_FRAG(saccB, mB, mcB, lB, oacB, (&sP[1][0]));                    \
        __builtin_amdgcn_s_setprio(1);                                          \
        {                                                                       \
            bf16x8 pfA = *(const bf16x8*)&sP[0][lofs0];                         \
            bf16x8 pfB = *(const bf16x8*)&sP[1][lofs0];                         \
            _Pragma("unroll")                                                   \
            for (int dt = 0; dt < 4; ++dt) {                                    \
                bf16x8 vf = *(const bf16x8*)(vRun + (size_t)(dt * 16) * S_LEN); \
                oacA[dt] = __builtin_amdgcn_mfma_f32_16x16x32_bf16(             \
                    vf, pfA, oacA[dt], 0, 0, 0);                                \
                oacB[dt] = __builtin_amdgcn_mfma_f32_16x16x32_bf16(             \
                    vf, pfB, oacB[dt], 0, 0, 0);                                \
            }                                                                   \
            pfA = *(const bf16x8*)&sP[0][lofs1];                                \
            pfB = *(const bf16x8*)&sP[1][lofs1];                                \
            _Pragma("unroll")                                                   \
            for (int dt = 0; dt < 4; ++dt) {                                    \
                bf16x8 vf = *(const bf16x8*)(vRun + (size_t)(dt * 16) * S_LEN + 32); \
                oacA[dt] = __builtin_amdgcn_mfma_f32_16x16x32_bf16(             \
                    vf, pfA, oacA[dt], 0, 0, 0);                                \
                oacB[dt] = __builtin_amdgcn_mfma_f32_16x16x32_bf16(             \
                    vf, pfB, oacB[dt], 0, 0, 0);                                \
            }                                                                   \
        }                                                                       \
        __builtin_amdgcn_s_setprio(0);                                          \
    } while (0)

    for (int t = 0; t < nT; ++t) {
        if (t < nFull) TILE_BODY(false);
        else TILE_BODY(true);
        kRun += 64 * DMODEL;
        vRun += 64;
    }
#undef TILE_BODY
#undef SOFTMAX_FRAG

    // total denominator per own q: sum partials across the 4 column-group lanes
    float ltA = lA + __shfl_xor(lA, 16);
    ltA += __shfl_xor(ltA, 32);
    float rlA = 1.f / ltA;
    float ltB = lB + __shfl_xor(lB, 16);
    ltB += __shfl_xor(ltB, 32);
    float rlB = 1.f / ltB;

    short* orowA = O + rowbase + (size_t)(qb * 32 + lr) * DMODEL;
    short* orowB = orowA + 16 * DMODEL;
#pragma unroll
    for (int dt = 0; dt < 4; ++dt) {
        short4v pkA, pkB;
#pragma unroll
        for (int j = 0; j < 4; ++j) {
            pkA[j] = f2b(oacA[dt][j] * rlA);
            pkB[j] = f2b(oacB[dt][j] * rlB);
        }
        *(short4v*)&orowA[dt * 16 + rbase] = pkA;
        *(short4v*)&orowB[dt * 16 + rbase] = pkB;
    }
}

extern "C" void kernel_launch(void* const* d_in, const int* in_sizes, int n_in,
                              void* d_out, int out_size, void* d_ws, size_t ws_size,
                              hipStream_t stream) {
    const float* X = (const float*)d_in[0];
    const int* vlens = (const int*)d_in[1];
    const float* Wq = (const float*)d_in[2];
    const float* Wk = (const float*)d_in[3];
    const float* Wv = (const float*)d_in[4];
    const float* Wo = (const float*)d_in[5];
    float* out = (float*)d_out;

    short* Xb = (short*)d_ws;
    short* Wqb = Xb + (size_t)MROWS * DMODEL;
    short* Wkb = Wqb + (size_t)DMODEL * DMODEL;
    short* Wvb = Wkb + (size_t)DMODEL * DMODEL;
    short* Wob = Wvb + (size_t)DMODEL * DMODEL;
    short* Qb = Wob + (size_t)DMODEL * DMODEL;
    short* Kb = Qb + (size_t)MROWS * DMODEL;
    short* Vtb = Kb + (size_t)MROWS * DMODEL;  // Vt[b][h][d][key], same size
    short* Ob = Vtb + (size_t)MROWS * DMODEL;

    cvt_kernel<<<dim3(512, 5), 256, 0, stream>>>(X, Wq, Wk, Wv, Wo, Xb, Wqb, Wkb,
                                                 Wvb, Wob);
    gemm_bt<0><<<dim3(8, 32, 3), 256, 0, stream>>>(Xb, Wqb, Wkb, Wvb, Qb, Kb, Vtb,
                                                   nullptr, MROWS, DMODEL, DMODEL);
    attn_kernel<<<dim3(2048), 64, 0, stream>>>(Qb, Kb, Vtb, Ob, vlens);
    gemm_bt<1><<<dim3(8, 32, 1), 256, 0, stream>>>(Ob, Wob, Wob, Wob, nullptr,
                                                   nullptr, nullptr, out, MROWS,
                                                   DMODEL, DMODEL);
}

// Round 12
// 104.489 us; speedup vs baseline: 1.5883x; 1.5883x over previous
//
#include <hip/hip_runtime.h>
#include <stdint.h>

#define S_LEN 2048
#define BATCH 2
#define DMODEL 1024
#define NHEAD 16
#define DK 64
#define MROWS (BATCH * S_LEN) /* 4096 */

typedef __attribute__((ext_vector_type(8))) short bf16x8;
typedef __attribute__((ext_vector_type(4))) float f32x4;
typedef __attribute__((ext_vector_type(4))) short short4v;
typedef __attribute__((ext_vector_type(2))) uint32_t u32x2;

#define VMCNT(N) asm volatile("s_waitcnt vmcnt(" #N ")" ::: "memory")

__device__ __forceinline__ short f2b(float f) {
    union { float f; uint32_t u; } c; c.f = f;
    uint32_t u = c.u;
    return (short)((u + 0x7fffu + ((u >> 16) & 1u)) >> 16);
}

__device__ __forceinline__ void gload16(const void* g, void* l) {
    __builtin_amdgcn_global_load_lds(
        (const __attribute__((address_space(1))) void*)g,
        (__attribute__((address_space(3))) void*)l, 16, 0, 0);
}

// ---------------------------------------------------------------- fp32 -> bf16
__global__ void cvt_kernel(const float* __restrict__ X, const float* __restrict__ Wq,
                           const float* __restrict__ Wk, const float* __restrict__ Wv,
                           const float* __restrict__ Wo,
                           short* __restrict__ Xb, short* __restrict__ Wqb,
                           short* __restrict__ Wkb, short* __restrict__ Wvb,
                           short* __restrict__ Wob) {
    const float* src; short* dst; int n4;
    switch (blockIdx.y) {
        case 0:  src = X;  dst = Xb;  n4 = MROWS * DMODEL / 4;  break;
        case 1:  src = Wq; dst = Wqb; n4 = DMODEL * DMODEL / 4; break;
        case 2:  src = Wk; dst = Wkb; n4 = DMODEL * DMODEL / 4; break;
        case 3:  src = Wv; dst = Wvb; n4 = DMODEL * DMODEL / 4; break;
        default: src = Wo; dst = Wob; n4 = DMODEL * DMODEL / 4; break;
    }
    for (int i = blockIdx.x * blockDim.x + threadIdx.x; i < n4;
         i += gridDim.x * blockDim.x) {
        float4 v = ((const float4*)src)[i];
        short4v o;
        o[0] = f2b(v.x); o[1] = f2b(v.y); o[2] = f2b(v.z); o[3] = f2b(v.w);
        ((short4v*)dst)[i] = o;
    }
}

// ------------------------------------------------- C = A * Bt^T  (bf16 MFMA)
// 3-deep LDS pipeline, counted vmcnt (never 0 mid-loop) + raw s_barrier:
// per K-step: VMCNT(4) -> barrier -> issue loads(kt+2) -> compute(kt).
// XOR-swizzled tiles (conflicts=0, verified R8). z==2 writes Vt[b][h][d][key].
template <int OUT_F32>
__global__ __launch_bounds__(256) void gemm_bt(
    const short* __restrict__ A,
    const short* __restrict__ Bt0, const short* __restrict__ Bt1,
    const short* __restrict__ Bt2,
    short* __restrict__ Cb0, short* __restrict__ Cb1, short* __restrict__ Cb2,
    float* __restrict__ Cf, int M, int N, int K) {
    __shared__ short sA[3][128 * 32];
    __shared__ short sB[3][128 * 32];

    const short* Bt = Bt0;
    short* Cb = Cb0;
    if (blockIdx.z == 1) { Bt = Bt1; Cb = Cb1; }
    else if (blockIdx.z == 2) { Bt = Bt2; Cb = Cb2; }

    const int tid = threadIdx.x;
    const int lane = tid & 63;
    const int wid = tid >> 6;
    const int wr = wid >> 1, wc = wid & 1;
    const int brow = blockIdx.y * 128;
    const int bcol = blockIdx.x * 128;
    const int lr = lane & 15;
    const int kh = (lane >> 4) << 3;
    const int swg = ((lr >> 1) & 3) << 3;   // read-side swizzle (lane-invariant)
    const int khs = kh ^ swg;

    f32x4 acc[4][4] = {};

    const int idx0 = tid, idx1 = tid + 256;
    const int ar0 = idx0 >> 2, ak0 = ((idx0 & 3) << 3) ^ (((ar0 >> 1) & 3) << 3);
    const int ar1 = idx1 >> 2, ak1 = ((idx1 & 3) << 3) ^ (((ar1 >> 1) & 3) << 3);

    const short* gA0 = A + (size_t)(brow + ar0) * K + ak0;
    const short* gA1 = A + (size_t)(brow + ar1) * K + ak1;
    const short* gB0 = Bt + (size_t)(bcol + ar0) * K + ak0;
    const short* gB1 = Bt + (size_t)(bcol + ar1) * K + ak1;

#define G_STAGE(KT, PA, PB)                                   \
    do {                                                      \
        const int k0_ = (KT) << 5;                            \
        gload16(gA0 + k0_, (PA) + idx0 * 8);                  \
        gload16(gA1 + k0_, (PA) + idx1 * 8);                  \
        gload16(gB0 + k0_, (PB) + idx0 * 8);                  \
        gload16(gB1 + k0_, (PB) + idx1 * 8);                  \
    } while (0)

    const int nk = K >> 5;   // 32
    short* pA0 = &sA[0][0]; short* pA1 = &sA[1][0]; short* pA2 = &sA[2][0];
    short* pB0 = &sB[0][0]; short* pB1 = &sB[1][0]; short* pB2 = &sB[2][0];

    G_STAGE(0, pA0, pB0);
    G_STAGE(1, pA1, pB1);

    for (int kt = 0; kt < nk; ++kt) {
        if (kt == nk - 1) { VMCNT(0); } else { VMCNT(4); }
        __builtin_amdgcn_s_barrier();
        if (kt + 2 < nk) G_STAGE(kt + 2, pA2, pB2);

        bf16x8 a[4], b[4];
#pragma unroll
        for (int mt = 0; mt < 4; ++mt)
            a[mt] = *(const bf16x8*)&pA0[(wr * 64 + mt * 16 + lr) * 32 + khs];
#pragma unroll
        for (int nt = 0; nt < 4; ++nt)
            b[nt] = *(const bf16x8*)&pB0[(wc * 64 + nt * 16 + lr) * 32 + khs];
        __builtin_amdgcn_s_setprio(1);
#pragma unroll
        for (int mt = 0; mt < 4; ++mt)
#pragma unroll
            for (int nt = 0; nt < 4; ++nt)
                acc[mt][nt] = __builtin_amdgcn_mfma_f32_16x16x32_bf16(
                    a[mt], b[nt], acc[mt][nt], 0, 0, 0);
        __builtin_amdgcn_s_setprio(0);

        short* tA = pA0; pA0 = pA1; pA1 = pA2; pA2 = tA;
        short* tB = pB0; pB0 = pB1; pB1 = pB2; pB2 = tB;
    }
#undef G_STAGE

    const int rbase = (lane >> 4) << 2;
    const bool vtrans = (!OUT_F32) && (blockIdx.z == 2);
#pragma unroll
    for (int mt = 0; mt < 4; ++mt) {
#pragma unroll
        for (int nt = 0; nt < 4; ++nt) {
            if (vtrans) {
                int row0 = brow + wr * 64 + mt * 16 + rbase;  // key (4 consecutive)
                int col = bcol + wc * 64 + nt * 16 + lr;
                int bb = row0 >> 11, key = row0 & 2047;
                int hh = col >> 6, d = col & 63;
                short4v pk;
#pragma unroll
                for (int j = 0; j < 4; ++j) pk[j] = f2b(acc[mt][nt][j]);
                *(short4v*)&Cb[((size_t)((bb * 16 + hh) * 64 + d)) * S_LEN + key] = pk;
            } else {
#pragma unroll
                for (int j = 0; j < 4; ++j) {
                    int row = brow + wr * 64 + mt * 16 + rbase + j;
                    int col = bcol + wc * 64 + nt * 16 + lr;
                    if (OUT_F32)
                        Cf[(size_t)row * N + col] = acc[mt][nt][j];
                    else
                        Cb[(size_t)row * N + col] = f2b(acc[mt][nt][j]);
                }
            }
        }
    }
}

// ------------------------------------------------------------- flash attention
// 512 blocks x 4 waves; wave owns 32 q-rows as two 16-row fragments sharing
// every K/V LDS read. 3-deep K/V pipeline with counted vmcnt + raw barrier
// (one barrier/tile, never vmcnt(0) mid-loop). Block mapping puts the two
// co-resident blocks of a CU on OPPOSITE batches (vl-tail balance) and pins
// each (b,h) group to one XCD. Swapped QK^T / swapped PV, lane-local softmax,
// defer-max THR=8.
__global__ __launch_bounds__(256) void attn_kernel(
    const short* __restrict__ Q, const short* __restrict__ K,
    const short* __restrict__ Vt, short* __restrict__ O,
    const int* __restrict__ vlens) {
    __shared__ short sK[3][64 * 64];
    __shared__ short sV[3][64 * 64];
    __shared__ short sP[4][2][16 * 64];

    const int tid = threadIdx.x;
    const int lane = tid & 63;
    const int w = tid >> 6;
    // mapping: xcd = id&7; r = id>>3; b = r bit5 (CU-pair batch mix);
    // h = xcd*2 + (r&1); qb = (r>>1)&15  -> 2MB K/V footprint per XCD.
    const int id = blockIdx.x;
    const int xcd = id & 7;
    const int r = id >> 3;
    const int b = (r >> 5) & 1;
    const int h = (xcd << 1) | (r & 1);
    const int qb = (r >> 1) & 15;          // 16 q-tiles of 128 rows
    const int lr = lane & 15;
    const int kh = (lane >> 4) << 3;
    const int rbase = (lane >> 4) << 2;
    const int swq = (lr & 7) << 3;

    int vl = vlens[b];
    if (vl < 0) vl = 0;
    if (vl > S_LEN) vl = S_LEN;
    const bool allm = (vl == 0);
    if (allm) vl = S_LEN;  // qf=0 -> scores 0 -> uniform softmax == reference
    const int nT = (vl + 63) >> 6;
    const int nFull = ((vl & 63) == 0) ? nT : nT - 1;

    const size_t rowbase = (size_t)(b * S_LEN) * DMODEL + h * DK;
    const short* vt = Vt + ((size_t)((b * 16 + h) * 64)) * S_LEN;

    const short* qrowA = Q + rowbase + (size_t)(qb * 128 + w * 32 + lr) * DMODEL;
    const short* qrowB = qrowA + 16 * DMODEL;
    bf16x8 qf0a = *(const bf16x8*)(qrowA + kh);
    bf16x8 qf1a = *(const bf16x8*)(qrowA + 32 + kh);
    bf16x8 qf0b = *(const bf16x8*)(qrowB + kh);
    bf16x8 qf1b = *(const bf16x8*)(qrowB + 32 + kh);
    if (allm) {
#pragma unroll
        for (int i = 0; i < 8; ++i) { qf0a[i] = 0; qf1a[i] = 0; qf0b[i] = 0; qf1b[i] = 0; }
    }

    f32x4 oacA[4] = {}, oacB[4] = {};
    float mA = -1e30f, mcA = -1e30f, lA = 0.f;
    float mB = -1e30f, mcB = -1e30f, lB = 0.f;
    const float CEXP = 0.18033688011112042f;   // 0.125 * log2(e)
    const float THRADD = 44.361419556f;        // 8 / CEXP

    // lane-resolved loop-invariant LDS read offsets (in shorts)
    const int lofs0 = lr * 64 + (kh ^ swq);
    const int lofs1 = lr * 64 + ((32 + kh) ^ swq);

    // staging: 256 thr x 2 chunks each for K and V (4 gload16/wave/tile)
    const int kr = tid >> 3;                       // 0..31
    const int kc = (((tid & 7) ^ (kr & 7)) << 3);  // pre-swizzled col (rows 32+ same &7)
    const short* kBase = K + rowbase + (size_t)kr * DMODEL + kc;
    const short* vBase = vt + (size_t)kr * S_LEN + kc;

#define A_STAGE(T, PK, PV)                                                      \
    do {                                                                        \
        const short* kg_ = kBase + (size_t)((T) * 64) * DMODEL;                 \
        gload16(kg_, (PK) + tid * 8);                                           \
        gload16(kg_ + (size_t)32 * DMODEL, (PK) + (tid + 256) * 8);             \
        const short* vg_ = vBase + (T) * 64;                                    \
        gload16(vg_, (PV) + tid * 8);                                           \
        gload16(vg_ + (size_t)32 * S_LEN, (PV) + (tid + 256) * 8);              \
    } while (0)

#define SOFTMAX_FRAG(SACC, MRUN, MC, LRUN, OAC, SPW)                            \
    do {                                                                        \
        float t0 = fmaxf(fmaxf(SACC[0][0], SACC[0][1]), SACC[0][2]);            \
        float t1 = fmaxf(fmaxf(SACC[0][3], SACC[1][0]), SACC[1][1]);            \
        float t2 = fmaxf(fmaxf(SACC[1][2], SACC[1][3]), SACC[2][0]);            \
        float t3 = fmaxf(fmaxf(SACC[2][1], SACC[2][2]), SACC[2][3]);            \
        float t4 = fmaxf(fmaxf(SACC[3][0], SACC[3][1]), SACC[3][2]);            \
        float pmax = fmaxf(fmaxf(fmaxf(t0, t1), t2),                            \
                           fmaxf(fmaxf(t3, t4), SACC[3][3]));                   \
        if (__any(pmax > MRUN + THRADD)) {                                      \
            float mx = pmax;                                                    \
            mx = fmaxf(mx, __shfl_xor(mx, 16));                                 \
            mx = fmaxf(mx, __shfl_xor(mx, 32));                                 \
            float scl = __builtin_exp2f((MRUN - mx) * CEXP);                    \
            MRUN = mx;                                                          \
            MC = mx * CEXP;                                                     \
            LRUN *= scl;                                                        \
            _Pragma("unroll")                                                   \
            for (int dt = 0; dt < 4; ++dt)                                      \
                _Pragma("unroll")                                               \
                for (int j = 0; j < 4; ++j) OAC[dt][j] *= scl;                  \
        }                                                                       \
        float p[16];                                                            \
        _Pragma("unroll")                                                       \
        for (int nt = 0; nt < 4; ++nt)                                          \
            _Pragma("unroll")                                                   \
            for (int j = 0; j < 4; ++j)                                         \
                p[nt * 4 + j] = __builtin_exp2f(                                \
                    __builtin_fmaf(SACC[nt][j], CEXP, -MC));                    \
        float ls = ((p[0] + p[1]) + (p[2] + p[3])) +                            \
                   ((p[4] + p[5]) + (p[6] + p[7]));                             \
        ls += ((p[8] + p[9]) + (p[10] + p[11])) +                               \
              ((p[12] + p[13]) + (p[14] + p[15]));                              \
        LRUN += ls;                                                             \
        _Pragma("unroll")                                                       \
        for (int nt = 0; nt < 4; ++nt) {                                        \
            u32x2 r_;                                                           \
            asm("v_cvt_pk_bf16_f32 %0, %1, %2"                                  \
                : "=v"(r_[0]) : "v"(p[nt * 4 + 0]), "v"(p[nt * 4 + 1]));        \
            asm("v_cvt_pk_bf16_f32 %0, %1, %2"                                  \
                : "=v"(r_[1]) : "v"(p[nt * 4 + 2]), "v"(p[nt * 4 + 3]));        \
            *(u32x2*)&SPW[lr * 64 + ((nt * 16 + rbase) ^ swq)] = r_;            \
        }                                                                       \
    } while (0)

#define TILE_BODY(MASKED_C, PK, PV)                                             \
    do {                                                                        \
        constexpr bool MASKED = MASKED_C;                                       \
        const short* kL0 = (PK) + lofs0;                                        \
        const short* kL1 = (PK) + lofs1;                                        \
        f32x4 saccA[4] = {}, saccB[4] = {};                                     \
        __builtin_amdgcn_s_setprio(1);                                          \
        _Pragma("unroll")                                                       \
        for (int nt = 0; nt < 4; ++nt) {                                        \
            bf16x8 kb0 = *(const bf16x8*)&kL0[nt * 1024];                       \
            bf16x8 kb1 = *(const bf16x8*)&kL1[nt * 1024];                       \
            saccA[nt] = __builtin_amdgcn_mfma_f32_16x16x32_bf16(                \
                kb0, qf0a, saccA[nt], 0, 0, 0);                                 \
            saccB[nt] = __builtin_amdgcn_mfma_f32_16x16x32_bf16(                \
                kb0, qf0b, saccB[nt], 0, 0, 0);                                 \
            saccA[nt] = __builtin_amdgcn_mfma_f32_16x16x32_bf16(                \
                kb1, qf1a, saccA[nt], 0, 0, 0);                                 \
            saccB[nt] = __builtin_amdgcn_mfma_f32_16x16x32_bf16(                \
                kb1, qf1b, saccB[nt], 0, 0, 0);                                 \
        }                                                                       \
        __builtin_amdgcn_s_setprio(0);                                          \
        if (MASKED) {                                                           \
            _Pragma("unroll")                                                   \
            for (int nt = 0; nt < 4; ++nt)                                      \
                _Pragma("unroll")                                               \
                for (int j = 0; j < 4; ++j) {                                   \
                    int keyi = t * 64 + nt * 16 + rbase + j;                    \
                    if (keyi >= vl) { saccA[nt][j] = -3.0e38f;                  \
                                      saccB[nt][j] = -3.0e38f; }                \
                }                                                               \
        }                                                                       \
        SOFTMAX_FRAG(saccA, mA, mcA, lA, oacA, (&sP[w][0][0]));                 \
        SOFTMAX_FRAG(saccB, mB, mcB, lB, oacB, (&sP[w][1][0]));                 \
        const short* vL0 = (PV) + lofs0;                                        \
        const short* vL1 = (PV) + lofs1;                                        \
        __builtin_amdgcn_s_setprio(1);                                          \
        {                                                                       \
            bf16x8 pfA = *(const bf16x8*)&sP[w][0][lofs0];                      \
            bf16x8 pfB = *(const bf16x8*)&sP[w][1][lofs0];                      \
            _Pragma("unroll")                                                   \
            for (int dt = 0; dt < 4; ++dt) {                                    \
                bf16x8 vf = *(const bf16x8*)&vL0[dt * 1024];                    \
                oacA[dt] = __builtin_amdgcn_mfma_f32_16x16x32_bf16(             \
                    vf, pfA, oacA[dt], 0, 0, 0);                                \
                oacB[dt] = __builtin_amdgcn_mfma_f32_16x16x32_bf16(             \
                    vf, pfB, oacB[dt], 0, 0, 0);                                \
            }                                                                   \
            pfA = *(const bf16x8*)&sP[w][0][lofs1];                             \
            pfB = *(const bf16x8*)&sP[w][1][lofs1];                             \
            _Pragma("unroll")                                                   \
            for (int dt = 0; dt < 4; ++dt) {                                    \
                bf16x8 vf = *(const bf16x8*)&vL1[dt * 1024];                    \
                oacA[dt] = __builtin_amdgcn_mfma_f32_16x16x32_bf16(             \
                    vf, pfA, oacA[dt], 0, 0, 0);                                \
                oacB[dt] = __builtin_amdgcn_mfma_f32_16x16x32_bf16(             \
                    vf, pfB, oacB[dt], 0, 0, 0);                                \
            }                                                                   \
        }                                                                       \
        __builtin_amdgcn_s_setprio(0);                                          \
    } while (0)

    short* pK0 = &sK[0][0]; short* pK1 = &sK[1][0]; short* pK2 = &sK[2][0];
    short* pV0 = &sV[0][0]; short* pV1 = &sV[1][0]; short* pV2 = &sV[2][0];

    A_STAGE(0, pK0, pV0);
    if (nT > 1) A_STAGE(1, pK1, pV1);

    for (int t = 0; t < nT; ++t) {
        if (t == nT - 1) { VMCNT(0); } else { VMCNT(4); }
        __builtin_amdgcn_s_barrier();
        if (t + 2 < nT) A_STAGE(t + 2, pK2, pV2);

        if (t < nFull) TILE_BODY(false, pK0, pV0);
        else TILE_BODY(true, pK0, pV0);

        short* tK = pK0; pK0 = pK1; pK1 = pK2; pK2 = tK;
        short* tV = pV0; pV0 = pV1; pV1 = pV2; pV2 = tV;
    }
#undef TILE_BODY
#undef SOFTMAX_FRAG
#undef A_STAGE

    // total denominator per own q: sum partials across the 4 column-group lanes
    float ltA = lA + __shfl_xor(lA, 16);
    ltA += __shfl_xor(ltA, 32);
    float rlA = 1.f / ltA;
    float ltB = lB + __shfl_xor(lB, 16);
    ltB += __shfl_xor(ltB, 32);
    float rlB = 1.f / ltB;

    short* orowA = O + rowbase + (size_t)(qb * 128 + w * 32 + lr) * DMODEL;
    short* orowB = orowA + 16 * DMODEL;
#pragma unroll
    for (int dt = 0; dt < 4; ++dt) {
        short4v pkA, pkB;
#pragma unroll
        for (int j = 0; j < 4; ++j) {
            pkA[j] = f2b(oacA[dt][j] * rlA);
            pkB[j] = f2b(oacB[dt][j] * rlB);
        }
        *(short4v*)&orowA[dt * 16 + rbase] = pkA;
        *(short4v*)&orowB[dt * 16 + rbase] = pkB;
    }
}

extern "C" void kernel_launch(void* const* d_in, const int* in_sizes, int n_in,
                              void* d_out, int out_size, void* d_ws, size_t ws_size,
                              hipStream_t stream) {
    const float* X = (const float*)d_in[0];
    const int* vlens = (const int*)d_in[1];
    const float* Wq = (const float*)d_in[2];
    const float* Wk = (const float*)d_in[3];
    const float* Wv = (const float*)d_in[4];
    const float* Wo = (const float*)d_in[5];
    float* out = (float*)d_out;

    short* Xb = (short*)d_ws;
    short* Wqb = Xb + (size_t)MROWS * DMODEL;
    short* Wkb = Wqb + (size_t)DMODEL * DMODEL;
    short* Wvb = Wkb + (size_t)DMODEL * DMODEL;
    short* Wob = Wvb + (size_t)DMODEL * DMODEL;
    short* Qb = Wob + (size_t)DMODEL * DMODEL;
    short* Kb = Qb + (size_t)MROWS * DMODEL;
    short* Vtb = Kb + (size_t)MROWS * DMODEL;  // Vt[b][h][d][key], same size
    short* Ob = Vtb + (size_t)MROWS * DMODEL;

    cvt_kernel<<<dim3(512, 5), 256, 0, stream>>>(X, Wq, Wk, Wv, Wo, Xb, Wqb, Wkb,
                                                 Wvb, Wob);
    gemm_bt<0><<<dim3(8, 32, 3), 256, 0, stream>>>(Xb, Wqb, Wkb, Wvb, Qb, Kb, Vtb,
                                                   nullptr, MROWS, DMODEL, DMODEL);
    attn_kernel<<<dim3(512), 256, 0, stream>>>(Qb, Kb, Vtb, Ob, vlens);
    gemm_bt<1><<<dim3(8, 32, 1), 256, 0, stream>>>(Ob, Wob, Wob, Wob, nullptr,
                                                   nullptr, nullptr, out, MROWS,
                                                   DMODEL, DMODEL);
}